// Round 1
// baseline (918.999 us; speedup 1.0000x reference)
//
#include <hip/hip_runtime.h>
#include <hip/hip_bf16.h>
#include <math.h>

typedef __bf16 bf16;
typedef __attribute__((ext_vector_type(8))) __bf16 bf16x8;
typedef __attribute__((ext_vector_type(4))) __bf16 bf16x4;
typedef __attribute__((ext_vector_type(4))) float f32x4;

#define BB 4
#define LL 4096
#define DD 1024
#define HH 8
#define HDIM 128
#define MTOK 16384
#define DFF 4096

#define BM 128
#define BN 128
#define BK 32

__device__ __forceinline__ void gload_lds16(const bf16* g, bf16* l) {
  __builtin_amdgcn_global_load_lds(
      (const __attribute__((address_space(1))) void*)g,
      (__attribute__((address_space(3))) void*)l, 16, 0, 0);
}

__device__ __forceinline__ float elu1f(float v) {
  // elu(v)+1 :  v>0 -> v+1 ; else exp(v)
  return v > 0.f ? v + 1.f : expf(v);
}
__device__ __forceinline__ float gelu_exact(float v) {
  return 0.5f * v * (1.f + erff(v * 0.70710678118654752f));
}

// ---------------------------------------------------------------------------
// Shared 128x128 (BK=32) bf16 MFMA GEMM core, B given TRANSPOSED ([N][K] rows).
// 256 threads = 4 waves in 2x2 grid; each wave computes a 64x64 quadrant as
// 4x4 fragments of v_mfma_f32_16x16x32_bf16.
// Fragment layouts (gfx950):
//   A/B: lane l, elem e: idx = l&15, k = 8*(l>>4)+e  (one contiguous bf16x8)
//   D  : lane l, reg r : col = l&15, row = 4*(l>>4)+r   [measured: learn_hip m89]
// ---------------------------------------------------------------------------
template <class EpiF>
__device__ __forceinline__ void gemm_bt_core(const bf16* __restrict__ A,
                                             const bf16* __restrict__ BT,
                                             int K, int m0, int n0, EpiF epi) {
  __shared__ bf16 As[BM * BK];
  __shared__ bf16 Bs[BN * BK];
  const int t = threadIdx.x;
  const int wv = t >> 6, lane = t & 63;
  const int fr = lane & 15, fg = lane >> 4;
  const int wm = (wv >> 1) * 64, wn = (wv & 1) * 64;

  const bf16* ga = A + (size_t)(m0 + (t >> 2)) * K + ((t & 3) << 3);
  const bf16* gb = BT + (size_t)(n0 + (t >> 2)) * K + ((t & 3) << 3);
  bf16* asw = As + wv * 512;  // wave-uniform LDS base; HW adds lane*16B
  bf16* bsw = Bs + wv * 512;

  f32x4 acc[4][4];
#pragma unroll
  for (int i = 0; i < 4; ++i)
#pragma unroll
    for (int j = 0; j < 4; ++j) acc[i][j] = (f32x4){0.f, 0.f, 0.f, 0.f};

  for (int k0 = 0; k0 < K; k0 += BK) {
    gload_lds16(ga + k0, asw);
    gload_lds16(ga + k0 + (size_t)64 * K, asw + 2048);
    gload_lds16(gb + k0, bsw);
    gload_lds16(gb + k0 + (size_t)64 * K, bsw + 2048);
    __syncthreads();
    bf16x8 af[4], bfr[4];
#pragma unroll
    for (int i = 0; i < 4; ++i)
      af[i] = *(const bf16x8*)(As + (wm + i * 16 + fr) * BK + fg * 8);
#pragma unroll
    for (int j = 0; j < 4; ++j)
      bfr[j] = *(const bf16x8*)(Bs + (wn + j * 16 + fr) * BK + fg * 8);
#pragma unroll
    for (int i = 0; i < 4; ++i)
#pragma unroll
      for (int j = 0; j < 4; ++j)
        acc[i][j] = __builtin_amdgcn_mfma_f32_16x16x32_bf16(af[i], bfr[j],
                                                            acc[i][j], 0, 0, 0);
    __syncthreads();
  }
#pragma unroll
  for (int i = 0; i < 4; ++i)
#pragma unroll
    for (int j = 0; j < 4; ++j)
#pragma unroll
      for (int r = 0; r < 4; ++r)
        epi(m0 + wm + i * 16 + fg * 4 + r, n0 + wn + j * 16 + fr, acc[i][j][r]);
}

// --------------------------- prep kernels ----------------------------------
__global__ __launch_bounds__(256) void k_conv_bf16(const float* __restrict__ xin,
                                                   bf16* __restrict__ xo) {
  int i = blockIdx.x * 256 + threadIdx.x;  // 4 elems each, grid sized exactly
  float4 v = ((const float4*)xin)[i];
  bf16x4 o = {(bf16)v.x, (bf16)v.y, (bf16)v.z, (bf16)v.w};
  *(bf16x4*)(xo + (size_t)i * 4) = o;
}

__global__ void k_transpose_w(const float* __restrict__ W, bf16* __restrict__ WTo,
                              int K, int N) {
  __shared__ float tile[32][33];
  int n0 = blockIdx.x * 32, k0 = blockIdx.y * 32;
  int x = threadIdx.x, y = threadIdx.y;  // 32x8
#pragma unroll
  for (int j = 0; j < 4; ++j)
    tile[y + 8 * j][x] = W[(size_t)(k0 + y + 8 * j) * N + n0 + x];
  __syncthreads();
#pragma unroll
  for (int j = 0; j < 4; ++j)
    WTo[(size_t)(n0 + y + 8 * j) * K + k0 + x] = (bf16)tile[x][y + 8 * j];
}

// --------------------------- GEMM kernels ----------------------------------
__global__ __launch_bounds__(256) void k_gemm_qkv(const bf16* __restrict__ xb,
                                                  const bf16* __restrict__ WT,
                                                  bf16* __restrict__ Q,
                                                  bf16* __restrict__ KT,
                                                  bf16* __restrict__ VT) {
  int m0 = blockIdx.y * BM, n0 = blockIdx.x * BN;
  gemm_bt_core(xb, WT, DD, m0, n0, [=](int r, int c, float v) {
    int b = r >> 12, l = r & (LL - 1);
    int which = c >> 10, cw = c & 1023, h = cw >> 7, d = cw & 127;
    size_t bh = (size_t)(b * HH + h);
    if (which == 0) {
      Q[(bh * LL + l) * HDIM + d] = (bf16)elu1f(v);
    } else if (which == 1) {
      KT[(bh * HDIM + d) * LL + l] = (bf16)elu1f(v);
    } else {
      VT[(bh * HDIM + d) * LL + l] = (bf16)v;
    }
  });
}

// kv^T[m][d] = sum_l k'[l][d] * v[l][m], one (b,h) per block (M=N=128, K=4096)
__global__ __launch_bounds__(256) void k_kv(const bf16* __restrict__ KT,
                                            const bf16* __restrict__ VT,
                                            bf16* __restrict__ kvT) {
  int bh = blockIdx.x;
  const bf16* A = KT + (size_t)bh * HDIM * LL;
  const bf16* Bt = VT + (size_t)bh * HDIM * LL;
  bf16* o = kvT + (size_t)bh * HDIM * HDIM;
  gemm_bt_core(A, Bt, LL, 0, 0,
               [=](int r, int c, float v) { o[c * HDIM + r] = (bf16)v; });
}

__global__ __launch_bounds__(256) void k_ksum(const bf16* __restrict__ KT,
                                              float* __restrict__ ksum) {
  int row = blockIdx.x;  // bh*128 + d, rows of KT
  const bf16* p = KT + (size_t)row * LL;
  int t = threadIdx.x;
  bf16x8 v0 = *(const bf16x8*)(p + t * 16);
  bf16x8 v1 = *(const bf16x8*)(p + t * 16 + 8);
  float s = 0.f;
#pragma unroll
  for (int i = 0; i < 8; ++i) s += (float)v0[i] + (float)v1[i];
  for (int off = 32; off > 0; off >>= 1) s += __shfl_down(s, off);
  __shared__ float wpart[4];
  int lane = t & 63, wv = t >> 6;
  if (lane == 0) wpart[wv] = s;
  __syncthreads();
  if (t == 0) ksum[row] = wpart[0] + wpart[1] + wpart[2] + wpart[3];
}

// out[l][m] = (q' @ kvT^T)[l][m] / (q'[l]·ksum + 1e-8)  -> attn[b,l, h*128+m]
__global__ __launch_bounds__(256) void k_attn_out(const bf16* __restrict__ Q,
                                                  const bf16* __restrict__ kvT,
                                                  const float* __restrict__ ksum,
                                                  bf16* __restrict__ attn) {
  const int bh = blockIdx.x, m0 = blockIdx.y * BM;
  const int b = bh >> 3, h = bh & 7;
  const bf16* A = Q + (size_t)bh * LL * HDIM;        // [4096][128]
  const bf16* Bt = kvT + (size_t)bh * HDIM * HDIM;   // [m][d]
  __shared__ bf16 As[BM * BK];
  __shared__ bf16 Bs[BN * BK];
  __shared__ float ksum_s[HDIM];
  __shared__ float norm_s[BM];
  const int t = threadIdx.x, wv = t >> 6, lane = t & 63;
  const int fr = lane & 15, fg = lane >> 4;
  const int wm = (wv >> 1) * 64, wn = (wv & 1) * 64;
  if (t < HDIM) ksum_s[t] = ksum[bh * HDIM + t];
  const bf16* ga = A + (size_t)(m0 + (t >> 2)) * HDIM + ((t & 3) << 3);
  const bf16* gb = Bt + (size_t)(t >> 2) * HDIM + ((t & 3) << 3);
  bf16* asw = As + wv * 512;
  bf16* bsw = Bs + wv * 512;
  f32x4 acc[4][4];
#pragma unroll
  for (int i = 0; i < 4; ++i)
#pragma unroll
    for (int j = 0; j < 4; ++j) acc[i][j] = (f32x4){0.f, 0.f, 0.f, 0.f};
  float nacc = 0.f;
  for (int k0 = 0; k0 < HDIM; k0 += BK) {
    gload_lds16(ga + k0, asw);
    gload_lds16(ga + k0 + 64 * HDIM, asw + 2048);
    gload_lds16(gb + k0, bsw);
    gload_lds16(gb + k0 + 64 * HDIM, bsw + 2048);
    __syncthreads();
    bf16x8 af[4], bfr[4];
#pragma unroll
    for (int i = 0; i < 4; ++i)
      af[i] = *(const bf16x8*)(As + (wm + i * 16 + fr) * BK + fg * 8);
#pragma unroll
    for (int j = 0; j < 4; ++j)
      bfr[j] = *(const bf16x8*)(Bs + (wn + j * 16 + fr) * BK + fg * 8);
#pragma unroll
    for (int i = 0; i < 4; ++i)
#pragma unroll
      for (int j = 0; j < 4; ++j)
        acc[i][j] = __builtin_amdgcn_mfma_f32_16x16x32_bf16(af[i], bfr[j],
                                                            acc[i][j], 0, 0, 0);
    if (t < BM) {  // normalizer partial: q'[row t] · ksum[k0..k0+31]
#pragma unroll
      for (int j = 0; j < BK; ++j) nacc += (float)As[t * BK + j] * ksum_s[k0 + j];
    }
    __syncthreads();
  }
  if (t < BM) norm_s[t] = nacc;
  __syncthreads();
#pragma unroll
  for (int i = 0; i < 4; ++i)
#pragma unroll
    for (int j = 0; j < 4; ++j)
#pragma unroll
      for (int r = 0; r < 4; ++r) {
        int rl = wm + i * 16 + fg * 4 + r;
        int c = wn + j * 16 + fr;
        float denom = norm_s[rl] + 1e-8f;
        attn[((size_t)b * LL + m0 + rl) * DD + h * HDIM + c] =
            (bf16)(acc[i][j][r] / denom);
      }
}

__global__ __launch_bounds__(256) void k_gemm_wout(const bf16* __restrict__ attn,
                                                   const bf16* __restrict__ WT,
                                                   const float* __restrict__ x,
                                                   bf16* __restrict__ z) {
  int m0 = blockIdx.y * BM, n0 = blockIdx.x * BN;
  gemm_bt_core(attn, WT, DD, m0, n0, [=](int r, int c, float v) {
    size_t idx = (size_t)r * DD + c;
    z[idx] = (bf16)(v + x[idx]);
  });
}

__global__ __launch_bounds__(256) void k_gemm_ff1(const bf16* __restrict__ y1,
                                                  const bf16* __restrict__ WT,
                                                  bf16* __restrict__ hbuf) {
  int m0 = blockIdx.y * BM, n0 = blockIdx.x * BN;
  gemm_bt_core(y1, WT, DD, m0, n0, [=](int r, int c, float v) {
    hbuf[(size_t)r * DFF + c] = (bf16)gelu_exact(v);
  });
}

__global__ __launch_bounds__(256) void k_gemm_ff2(const bf16* __restrict__ hbuf,
                                                  const bf16* __restrict__ WT,
                                                  const bf16* __restrict__ y1,
                                                  bf16* __restrict__ z2) {
  int m0 = blockIdx.y * BM, n0 = blockIdx.x * BN;
  gemm_bt_core(hbuf, WT, DFF, m0, n0, [=](int r, int c, float v) {
    size_t idx = (size_t)r * DD + c;
    z2[idx] = (bf16)(v + (float)y1[idx]);
  });
}

// --------------------------- RMSNorm ---------------------------------------
template <typename OUT>
__global__ __launch_bounds__(256) void k_rmsnorm(const bf16* __restrict__ zin,
                                                 const float* __restrict__ g,
                                                 OUT* __restrict__ y) {
  const int row = blockIdx.x, t = threadIdx.x;
  const bf16* zr = zin + (size_t)row * DD;
  bf16x4 v = *(const bf16x4*)(zr + t * 4);
  float f0 = (float)v[0], f1 = (float)v[1], f2 = (float)v[2], f3 = (float)v[3];
  float ss = f0 * f0 + f1 * f1 + f2 * f2 + f3 * f3;
  for (int off = 32; off > 0; off >>= 1) ss += __shfl_down(ss, off);
  __shared__ float wsum[4];
  __shared__ float stot;
  int lane = t & 63, wv = t >> 6;
  if (lane == 0) wsum[wv] = ss;
  __syncthreads();
  if (t == 0) stot = wsum[0] + wsum[1] + wsum[2] + wsum[3];
  __syncthreads();
  float scale = rsqrtf(stot * (1.f / DD) + 1.1920929e-7f);
  size_t base = (size_t)row * DD + t * 4;
  y[base + 0] = (OUT)(f0 * scale * g[t * 4 + 0]);
  y[base + 1] = (OUT)(f1 * scale * g[t * 4 + 1]);
  y[base + 2] = (OUT)(f2 * scale * g[t * 4 + 2]);
  y[base + 3] = (OUT)(f3 * scale * g[t * 4 + 3]);
}

// ---------------------------------------------------------------------------
extern "C" void kernel_launch(void* const* d_in, const int* in_sizes, int n_in,
                              void* d_out, int out_size, void* d_ws, size_t ws_size,
                              hipStream_t stream) {
  (void)in_sizes; (void)n_in; (void)out_size; (void)ws_size;
  const float* x    = (const float*)d_in[0];
  const float* Wqkv = (const float*)d_in[1];
  const float* Wout = (const float*)d_in[2];
  const float* g1   = (const float*)d_in[3];
  const float* Wff1 = (const float*)d_in[4];
  const float* Wff2 = (const float*)d_in[5];
  const float* g2   = (const float*)d_in[6];
  float* out = (float*)d_out;

  char* ws = (char*)d_ws;
  const size_t MB = 1ull << 20;
  bf16* WqkvT = (bf16*)(ws + 0);         // 6 MB  [3072][1024]
  bf16* WoutT = (bf16*)(ws + 6 * MB);    // 2 MB  [1024][1024]
  bf16* Wff1T = (bf16*)(ws + 8 * MB);    // 8 MB  [4096][1024]
  bf16* Wff2T = (bf16*)(ws + 16 * MB);   // 8 MB  [1024][4096]
  bf16* xb    = (bf16*)(ws + 24 * MB);   // 32 MB [16384][1024]   (dead after QKV)
  bf16* Q     = (bf16*)(ws + 56 * MB);   // 32 MB [b,h,l,d]       (dead after attn_out)
  bf16* KT    = (bf16*)(ws + 88 * MB);   // 32 MB [b,h,d,l]       (dead after kv/ksum)
  bf16* VT    = (bf16*)(ws + 120 * MB);  // 32 MB [b,h,d,l]       (dead after kv)
  bf16* attn  = xb;                      // alias: xb dead by the time attn is written
  bf16* hbuf  = (bf16*)(ws + 24 * MB);   // 128 MB [16384][4096], aliases all of R1
  bf16* kvT   = (bf16*)(ws + 152 * MB);  // 1 MB  [bh][m][d]
  float* ksum = (float*)(ws + 153 * MB); // 16 KB [bh][d]
  bf16* z     = (bf16*)(ws + 154 * MB);  // 32 MB pre-rms1 (dead after rms1)
  bf16* z2    = z;                       // alias
  bf16* y1    = (bf16*)(ws + 186 * MB);  // 32 MB rms1 output (live through ff2)

  // prep: bf16 casts + weight transposes
  k_conv_bf16<<<16384, 256, 0, stream>>>(x, xb);
  dim3 tb(32, 8);
  k_transpose_w<<<dim3(3072 / 32, 1024 / 32), tb, 0, stream>>>(Wqkv, WqkvT, 1024, 3072);
  k_transpose_w<<<dim3(1024 / 32, 1024 / 32), tb, 0, stream>>>(Wout, WoutT, 1024, 1024);
  k_transpose_w<<<dim3(4096 / 32, 1024 / 32), tb, 0, stream>>>(Wff1, Wff1T, 1024, 4096);
  k_transpose_w<<<dim3(1024 / 32, 4096 / 32), tb, 0, stream>>>(Wff2, Wff2T, 4096, 1024);

  // QKV projection + elu+1 fused, scattered to Q / KT / VT
  k_gemm_qkv<<<dim3(3072 / BN, MTOK / BM), 256, 0, stream>>>(xb, WqkvT, Q, KT, VT);
  // linear attention
  k_kv<<<32, 256, 0, stream>>>(KT, VT, kvT);
  k_ksum<<<4096, 256, 0, stream>>>(KT, ksum);
  k_attn_out<<<dim3(32, LL / BM), 256, 0, stream>>>(Q, kvT, ksum, attn);
  // W_out + residual(x)
  k_gemm_wout<<<dim3(1024 / BN, MTOK / BM), 256, 0, stream>>>(attn, WoutT, x, z);
  k_rmsnorm<bf16><<<MTOK, 256, 0, stream>>>(z, g1, y1);
  // FFN
  k_gemm_ff1<<<dim3(4096 / BN, MTOK / BM), 256, 0, stream>>>(y1, Wff1T, hbuf);
  k_gemm_ff2<<<dim3(1024 / BN, MTOK / BM), 256, 0, stream>>>(hbuf, Wff2T, y1, z2);
  k_rmsnorm<float><<<MTOK, 256, 0, stream>>>(z2, g2, out);
}

// Round 5
// 773.868 us; speedup vs baseline: 1.1875x; 1.1875x over previous
//
#include <hip/hip_runtime.h>
#include <hip/hip_bf16.h>
#include <math.h>

typedef __bf16 bf16;
typedef __attribute__((ext_vector_type(8))) __bf16 bf16x8;
typedef __attribute__((ext_vector_type(4))) __bf16 bf16x4;
typedef __attribute__((ext_vector_type(4))) float f32x4;

#define BB 4
#define LL 4096
#define DD 1024
#define HH 8
#define HDIM 128
#define MTOK 16384
#define DFF 4096

__device__ __forceinline__ void gload_lds16(const bf16* g, bf16* l) {
  __builtin_amdgcn_global_load_lds(
      (const __attribute__((address_space(1))) void*)g,
      (__attribute__((address_space(3))) void*)l, 16, 0, 0);
}

__device__ __forceinline__ float elu1f(float v) {
  return v > 0.f ? v + 1.f : expf(v);
}
__device__ __forceinline__ float gelu_exact(float v) {
  return 0.5f * v * (1.f + erff(v * 0.70710678118654752f));
}

// ===========================================================================
// 256x256 8-phase bf16 GEMM core (plain-HIP port of the HK cdna4 schedule).
// B is TRANSPOSED ([N][K]). 512 threads = 8 waves (2M x 4N); per-wave 128x64.
// LDS 128 KiB: 2 dbuf x { A: 2 kk-panels, B: 2 kk-panels }, panel = 256x32 bf16
// = 16384 B.  (R4 bugfix: panel stride was 8192 -> overlapping panels.)
// st_16x32 swizzle: byte ^= ((byte>>9)&1)<<5 (= (row&8)<<2 within a panel).
// Per K-tile (BK=64): 4 phases = (mh,kk) quadrants, 16 MFMA each.
// Stages: p1 -> h(T+1,3)=B-kk1 ; p2..p4 -> h(T+2, A-kk0 / B-kk0 / A-kk1).
// vmcnt(6) at phase 4 only => all of K-tile T+1 landed, 3 half-tiles in flight.
// ===========================================================================
template <class EpiF>
__device__ __forceinline__ void gemm256_core(const bf16* __restrict__ A,
                                             const bf16* __restrict__ BT,
                                             int K, int m0, int n0, EpiF epi) {
  __shared__ __align__(16) char sm[131072];
  const int t = threadIdx.x;
  const int wid = t >> 6, lane = t & 63;
  const int fr = lane & 15, fg = lane >> 4;
  const int wm = wid >> 2, wn = wid & 3;
  const int NT = K >> 6;

  // staging source precompute (inverse-swizzled global addresses)
  const int q0 = wid * 1024 + lane * 16;
  const int q1 = q0 + 8192;
  const int L0 = q0 ^ (((q0 >> 9) & 1) << 5);
  const int L1 = q1 ^ (((q1 >> 9) & 1) << 5);
  const bf16* ga0 = A + (size_t)(m0 + (L0 >> 6)) * K + ((L0 & 63) >> 1);
  const bf16* ga1 = A + (size_t)(m0 + (L1 >> 6)) * K + ((L1 & 63) >> 1);
  const bf16* gb0 = BT + (size_t)(n0 + (L0 >> 6)) * K + ((L0 & 63) >> 1);
  const bf16* gb1 = BT + (size_t)(n0 + (L1 >> 6)) * K + ((L1 & 63) >> 1);
  char* ld_w = sm + wid * 1024;  // wave-uniform; HW adds lane*16

#define STAGE_(bufb, isB, kk, kt)                                           \
  do {                                                                      \
    char* d_ = ld_w + (bufb) * 65536 + (isB) * 32768 + (kk) * 16384;        \
    const bf16* s0_ = ((isB) ? gb0 : ga0) + (kt) * 64 + (kk) * 32;          \
    const bf16* s1_ = ((isB) ? gb1 : ga1) + (kt) * 64 + (kk) * 32;          \
    gload_lds16(s0_, (bf16*)d_);                                            \
    gload_lds16(s1_, (bf16*)(d_ + 8192));                                   \
  } while (0)

  f32x4 acc[8][4];
#pragma unroll
  for (int i = 0; i < 8; ++i)
#pragma unroll
    for (int j = 0; j < 4; ++j) acc[i][j] = (f32x4){0.f, 0.f, 0.f, 0.f};
  bf16x8 bfr[4];

#define PHASE_(bufb, MH, KK, LOADB, doStage, sB, sIsB, sKk, sKt, VMW)       \
  do {                                                                      \
    bf16x8 af[4];                                                           \
    _Pragma("unroll") for (int i = 0; i < 4; ++i) {                         \
      int r_ = wm * 128 + (MH) * 64 + i * 16 + fr;                          \
      int by_ = (bufb) * 65536 + (KK) * 16384 + r_ * 64 + fg * 16;          \
      by_ ^= (r_ & 8) << 2;                                                 \
      af[i] = *(const bf16x8*)(sm + by_);                                   \
    }                                                                       \
    if (LOADB) {                                                            \
      _Pragma("unroll") for (int j = 0; j < 4; ++j) {                       \
        int rn_ = wn * 64 + j * 16 + fr;                                    \
        int by_ =                                                           \
            (bufb) * 65536 + 32768 + (KK) * 16384 + rn_ * 64 + fg * 16;     \
        by_ ^= (rn_ & 8) << 2;                                              \
        bfr[j] = *(const bf16x8*)(sm + by_);                                \
      }                                                                     \
    }                                                                       \
    if (doStage) STAGE_(sB, sIsB, sKk, sKt);                                \
    if ((VMW) == 6) asm volatile("s_waitcnt vmcnt(6)" ::: "memory");        \
    else if ((VMW) == 0) asm volatile("s_waitcnt vmcnt(0)" ::: "memory");   \
    asm volatile("s_barrier" ::: "memory");                                 \
    asm volatile("s_waitcnt lgkmcnt(0)" ::: "memory");                      \
    __builtin_amdgcn_sched_barrier(0);                                      \
    __builtin_amdgcn_s_setprio(1);                                          \
    _Pragma("unroll") for (int i = 0; i < 4; ++i)                           \
        _Pragma("unroll") for (int j = 0; j < 4; ++j) acc[(MH)*4 + i][j] =  \
        __builtin_amdgcn_mfma_f32_16x16x32_bf16(af[i], bfr[j],              \
                                                acc[(MH)*4 + i][j], 0, 0, 0); \
    __builtin_amdgcn_s_setprio(0);                                          \
    asm volatile("s_barrier" ::: "memory");                                 \
  } while (0)

  // prologue: K-tile 0 (4 half-tiles) + 3 half-tiles of K-tile 1
  STAGE_(0, 0, 0, 0);
  STAGE_(0, 1, 0, 0);
  STAGE_(0, 0, 1, 0);
  STAGE_(0, 1, 1, 0);
  STAGE_(1, 0, 0, 1);
  STAGE_(1, 1, 0, 1);
  STAGE_(1, 0, 1, 1);
  asm volatile("s_waitcnt vmcnt(6)" ::: "memory");
  asm volatile("s_barrier" ::: "memory");

  for (int T = 0; T < NT; ++T) {
    const int bufb = T & 1, nb = bufb ^ 1;
    const bool s1 = (T + 1 < NT);
    const bool s2 = (T + 2 < NT);
    const int vmw = s2 ? 6 : (s1 ? 0 : -1);
    PHASE_(bufb, 0, 0, true, s1, nb, 1, 1, T + 1, -1);
    PHASE_(bufb, 1, 0, false, s2, bufb, 0, 0, T + 2, -1);
    PHASE_(bufb, 0, 1, true, s2, bufb, 1, 0, T + 2, -1);
    PHASE_(bufb, 1, 1, false, s2, bufb, 0, 1, T + 2, vmw);
  }
#undef PHASE_
#undef STAGE_

#pragma unroll
  for (int i = 0; i < 8; ++i)
#pragma unroll
    for (int j = 0; j < 4; ++j)
#pragma unroll
      for (int r = 0; r < 4; ++r)
        epi(m0 + wm * 128 + i * 16 + fg * 4 + r, n0 + wn * 64 + j * 16 + fr,
            acc[i][j][r]);
}

// bijective XCD swizzle (nwg % 8 == 0 for all our grids)
__device__ __forceinline__ void tile_of(int Nt, int& mt, int& nt) {
  int nwg = gridDim.x, bid = blockIdx.x;
  int wg = (bid & 7) * (nwg >> 3) + (bid >> 3);
  mt = wg / Nt;
  nt = wg - mt * Nt;
}

__global__ __launch_bounds__(512, 2) void k256_qkv(const bf16* __restrict__ xb,
                                                   const bf16* __restrict__ WT,
                                                   bf16* __restrict__ Q,
                                                   bf16* __restrict__ KT,
                                                   bf16* __restrict__ VT, int Nt) {
  int mt, nt;
  tile_of(Nt, mt, nt);
  gemm256_core(xb, WT, DD, mt * 256, nt * 256, [=](int r, int c, float v) {
    int b = r >> 12, l = r & (LL - 1);
    int which = c >> 10, cw = c & 1023, h = cw >> 7, d = cw & 127;
    size_t bh = (size_t)(b * HH + h);
    if (which == 0) {
      Q[(bh * LL + l) * HDIM + d] = (bf16)elu1f(v);
    } else if (which == 1) {
      KT[(bh * HDIM + d) * LL + l] = (bf16)elu1f(v);
    } else {
      VT[(bh * HDIM + d) * LL + l] = (bf16)v;
    }
  });
}

__global__ __launch_bounds__(512, 2) void k256_wout(const bf16* __restrict__ attn,
                                                    const bf16* __restrict__ WT,
                                                    const float* __restrict__ x,
                                                    bf16* __restrict__ z, int Nt) {
  int mt, nt;
  tile_of(Nt, mt, nt);
  gemm256_core(attn, WT, DD, mt * 256, nt * 256, [=](int r, int c, float v) {
    size_t idx = (size_t)r * DD + c;
    z[idx] = (bf16)(v + x[idx]);
  });
}

__global__ __launch_bounds__(512, 2) void k256_ff1(const bf16* __restrict__ y1,
                                                   const bf16* __restrict__ WT,
                                                   bf16* __restrict__ hbuf, int Nt) {
  int mt, nt;
  tile_of(Nt, mt, nt);
  gemm256_core(y1, WT, DD, mt * 256, nt * 256, [=](int r, int c, float v) {
    hbuf[(size_t)r * DFF + c] = (bf16)gelu_exact(v);
  });
}

__global__ __launch_bounds__(512, 2) void k256_ff2(const bf16* __restrict__ hbuf,
                                                   const bf16* __restrict__ WT,
                                                   const bf16* __restrict__ y1,
                                                   bf16* __restrict__ z2, int Nt) {
  int mt, nt;
  tile_of(Nt, mt, nt);
  gemm256_core(hbuf, WT, DFF, mt * 256, nt * 256, [=](int r, int c, float v) {
    size_t idx = (size_t)r * DD + c;
    z2[idx] = (bf16)(v + (float)y1[idx]);
  });
}

// ===========================================================================
// 128x128 (BK=32) core for the small attention GEMMs (R1-verified), with a
// Klen param for split-K.
// ===========================================================================
#define BM 128
#define BN 128
#define BK 32

template <class EpiF>
__device__ __forceinline__ void gemm_bt_core(const bf16* __restrict__ A,
                                             const bf16* __restrict__ BT,
                                             int K, int Klen, int m0, int n0,
                                             EpiF epi) {
  __shared__ bf16 As[BM * BK];
  __shared__ bf16 Bs[BN * BK];
  const int t = threadIdx.x;
  const int wv = t >> 6, lane = t & 63;
  const int fr = lane & 15, fg = lane >> 4;
  const int wm = (wv >> 1) * 64, wn = (wv & 1) * 64;

  const bf16* ga = A + (size_t)(m0 + (t >> 2)) * K + ((t & 3) << 3);
  const bf16* gb = BT + (size_t)(n0 + (t >> 2)) * K + ((t & 3) << 3);
  bf16* asw = As + wv * 512;
  bf16* bsw = Bs + wv * 512;

  f32x4 acc[4][4];
#pragma unroll
  for (int i = 0; i < 4; ++i)
#pragma unroll
    for (int j = 0; j < 4; ++j) acc[i][j] = (f32x4){0.f, 0.f, 0.f, 0.f};

  for (int k0 = 0; k0 < Klen; k0 += BK) {
    gload_lds16(ga + k0, asw);
    gload_lds16(ga + k0 + (size_t)64 * K, asw + 2048);
    gload_lds16(gb + k0, bsw);
    gload_lds16(gb + k0 + (size_t)64 * K, bsw + 2048);
    __syncthreads();
    bf16x8 af[4], bfrg[4];
#pragma unroll
    for (int i = 0; i < 4; ++i)
      af[i] = *(const bf16x8*)(As + (wm + i * 16 + fr) * BK + fg * 8);
#pragma unroll
    for (int j = 0; j < 4; ++j)
      bfrg[j] = *(const bf16x8*)(Bs + (wn + j * 16 + fr) * BK + fg * 8);
#pragma unroll
    for (int i = 0; i < 4; ++i)
#pragma unroll
      for (int j = 0; j < 4; ++j)
        acc[i][j] = __builtin_amdgcn_mfma_f32_16x16x32_bf16(af[i], bfrg[j],
                                                            acc[i][j], 0, 0, 0);
    __syncthreads();
  }
#pragma unroll
  for (int i = 0; i < 4; ++i)
#pragma unroll
    for (int j = 0; j < 4; ++j)
#pragma unroll
      for (int r = 0; r < 4; ++r)
        epi(m0 + wm + i * 16 + fg * 4 + r, n0 + wn + j * 16 + fr, acc[i][j][r]);
}

// --------------------------- prep kernels ----------------------------------
__global__ __launch_bounds__(256) void k_conv_bf16(const float* __restrict__ xin,
                                                   bf16* __restrict__ xo) {
  int i = blockIdx.x * 256 + threadIdx.x;
  float4 v = ((const float4*)xin)[i];
  bf16x4 o = {(bf16)v.x, (bf16)v.y, (bf16)v.z, (bf16)v.w};
  *(bf16x4*)(xo + (size_t)i * 4) = o;
}

__global__ void k_transpose_w(const float* __restrict__ W, bf16* __restrict__ WTo,
                              int K, int N) {
  __shared__ float tile[32][33];
  int n0 = blockIdx.x * 32, k0 = blockIdx.y * 32;
  int x = threadIdx.x, y = threadIdx.y;  // 32x8
#pragma unroll
  for (int j = 0; j < 4; ++j)
    tile[y + 8 * j][x] = W[(size_t)(k0 + y + 8 * j) * N + n0 + x];
  __syncthreads();
#pragma unroll
  for (int j = 0; j < 4; ++j)
    WTo[(size_t)(n0 + y + 8 * j) * K + k0 + x] = (bf16)tile[x][y + 8 * j];
}

// --------------------------- attention -------------------------------------
// split-K kv: chunk c of 8 over L; partial f32 [c][bh][m][d]
__global__ __launch_bounds__(256) void k_kv_split(const bf16* __restrict__ KT,
                                                  const bf16* __restrict__ VT,
                                                  float* __restrict__ pbuf) {
  int c = blockIdx.x >> 5;
  int bh = blockIdx.x & 31;
  const bf16* A = KT + (size_t)bh * HDIM * LL + c * 512;
  const bf16* Bt = VT + (size_t)bh * HDIM * LL + c * 512;
  float* o = pbuf + ((size_t)c * 32 + bh) * 16384;
  gemm_bt_core(A, Bt, LL, 512, 0, 0,
               [=](int r, int cc, float v) { o[cc * HDIM + r] = v; });
}

__global__ __launch_bounds__(256) void k_kv_reduce(const float* __restrict__ pbuf,
                                                   bf16* __restrict__ kvT) {
  int i = blockIdx.x * 256 + threadIdx.x;  // 32*16384 total
  float s = 0.f;
#pragma unroll
  for (int c = 0; c < 8; ++c) s += pbuf[(size_t)c * 524288 + i];
  kvT[i] = (bf16)s;
}

__global__ __launch_bounds__(256) void k_ksum(const bf16* __restrict__ KT,
                                              float* __restrict__ ksum) {
  int row = blockIdx.x;
  const bf16* p = KT + (size_t)row * LL;
  int t = threadIdx.x;
  bf16x8 v0 = *(const bf16x8*)(p + t * 16);
  bf16x8 v1 = *(const bf16x8*)(p + t * 16 + 8);
  float s = 0.f;
#pragma unroll
  for (int i = 0; i < 8; ++i) s += (float)v0[i] + (float)v1[i];
  for (int off = 32; off > 0; off >>= 1) s += __shfl_down(s, off);
  __shared__ float wpart[4];
  int lane = t & 63, wv = t >> 6;
  if (lane == 0) wpart[wv] = s;
  __syncthreads();
  if (t == 0) ksum[row] = wpart[0] + wpart[1] + wpart[2] + wpart[3];
}

__global__ __launch_bounds__(256) void k_attn_out(const bf16* __restrict__ Q,
                                                  const bf16* __restrict__ kvT,
                                                  const float* __restrict__ ksum,
                                                  bf16* __restrict__ attn) {
  const int bh = blockIdx.x, m0 = blockIdx.y * BM;
  const int b = bh >> 3, h = bh & 7;
  const bf16* A = Q + (size_t)bh * LL * HDIM;
  const bf16* Bt = kvT + (size_t)bh * HDIM * HDIM;
  __shared__ bf16 As[BM * BK];
  __shared__ bf16 Bs[BN * BK];
  __shared__ float ksum_s[HDIM];
  __shared__ float norm_s[BM];
  const int t = threadIdx.x, wv = t >> 6, lane = t & 63;
  const int fr = lane & 15, fg = lane >> 4;
  const int wm = (wv >> 1) * 64, wn = (wv & 1) * 64;
  if (t < HDIM) ksum_s[t] = ksum[bh * HDIM + t];
  const bf16* ga = A + (size_t)(m0 + (t >> 2)) * HDIM + ((t & 3) << 3);
  const bf16* gb = Bt + (size_t)(t >> 2) * HDIM + ((t & 3) << 3);
  bf16* asw = As + wv * 512;
  bf16* bsw = Bs + wv * 512;
  f32x4 acc[4][4];
#pragma unroll
  for (int i = 0; i < 4; ++i)
#pragma unroll
    for (int j = 0; j < 4; ++j) acc[i][j] = (f32x4){0.f, 0.f, 0.f, 0.f};
  float nacc = 0.f;
  for (int k0 = 0; k0 < HDIM; k0 += BK) {
    gload_lds16(ga + k0, asw);
    gload_lds16(ga + k0 + 64 * HDIM, asw + 2048);
    gload_lds16(gb + k0, bsw);
    gload_lds16(gb + k0 + 64 * HDIM, bsw + 2048);
    __syncthreads();
    bf16x8 af[4], bfrg[4];
#pragma unroll
    for (int i = 0; i < 4; ++i)
      af[i] = *(const bf16x8*)(As + (wm + i * 16 + fr) * BK + fg * 8);
#pragma unroll
    for (int j = 0; j < 4; ++j)
      bfrg[j] = *(const bf16x8*)(Bs + (wn + j * 16 + fr) * BK + fg * 8);
#pragma unroll
    for (int i = 0; i < 4; ++i)
#pragma unroll
      for (int j = 0; j < 4; ++j)
        acc[i][j] = __builtin_amdgcn_mfma_f32_16x16x32_bf16(af[i], bfrg[j],
                                                            acc[i][j], 0, 0, 0);
    if (t < BM) {
#pragma unroll
      for (int j = 0; j < BK; ++j) nacc += (float)As[t * BK + j] * ksum_s[k0 + j];
    }
    __syncthreads();
  }
  if (t < BM) norm_s[t] = nacc;
  __syncthreads();
#pragma unroll
  for (int i = 0; i < 4; ++i)
#pragma unroll
    for (int j = 0; j < 4; ++j)
#pragma unroll
      for (int r = 0; r < 4; ++r) {
        int rl = wm + i * 16 + fg * 4 + r;
        int c = wn + j * 16 + fr;
        float denom = norm_s[rl] + 1e-8f;
        attn[((size_t)b * LL + m0 + rl) * DD + h * HDIM + c] =
            (bf16)(acc[i][j][r] / denom);
      }
}

// --------------------------- RMSNorm ---------------------------------------
template <typename OUT>
__global__ __launch_bounds__(256) void k_rmsnorm(const bf16* __restrict__ zin,
                                                 const float* __restrict__ g,
                                                 OUT* __restrict__ y) {
  const int row = blockIdx.x, t = threadIdx.x;
  const bf16* zr = zin + (size_t)row * DD;
  bf16x4 v = *(const bf16x4*)(zr + t * 4);
  float f0 = (float)v[0], f1 = (float)v[1], f2 = (float)v[2], f3 = (float)v[3];
  float ss = f0 * f0 + f1 * f1 + f2 * f2 + f3 * f3;
  for (int off = 32; off > 0; off >>= 1) ss += __shfl_down(ss, off);
  __shared__ float wsum[4];
  __shared__ float stot;
  int lane = t & 63, wv = t >> 6;
  if (lane == 0) wsum[wv] = ss;
  __syncthreads();
  if (t == 0) stot = wsum[0] + wsum[1] + wsum[2] + wsum[3];
  __syncthreads();
  float scale = rsqrtf(stot * (1.f / DD) + 1.1920929e-7f);
  size_t base = (size_t)row * DD + t * 4;
  y[base + 0] = (OUT)(f0 * scale * g[t * 4 + 0]);
  y[base + 1] = (OUT)(f1 * scale * g[t * 4 + 1]);
  y[base + 2] = (OUT)(f2 * scale * g[t * 4 + 2]);
  y[base + 3] = (OUT)(f3 * scale * g[t * 4 + 3]);
}

// ---------------------------------------------------------------------------
extern "C" void kernel_launch(void* const* d_in, const int* in_sizes, int n_in,
                              void* d_out, int out_size, void* d_ws, size_t ws_size,
                              hipStream_t stream) {
  (void)in_sizes; (void)n_in; (void)out_size; (void)ws_size;
  const float* x    = (const float*)d_in[0];
  const float* Wqkv = (const float*)d_in[1];
  const float* Wout = (const float*)d_in[2];
  const float* g1   = (const float*)d_in[3];
  const float* Wff1 = (const float*)d_in[4];
  const float* Wff2 = (const float*)d_in[5];
  const float* g2   = (const float*)d_in[6];
  float* out = (float*)d_out;

  char* ws = (char*)d_ws;
  const size_t MB = 1ull << 20;
  bf16* WqkvT = (bf16*)(ws + 0);         // 6 MB  [3072][1024]
  bf16* WoutT = (bf16*)(ws + 6 * MB);    // 2 MB  [1024][1024]
  bf16* Wff1T = (bf16*)(ws + 8 * MB);    // 8 MB  [4096][1024]
  bf16* Wff2T = (bf16*)(ws + 16 * MB);   // 8 MB  [1024][4096]
  bf16* xb    = (bf16*)(ws + 24 * MB);   // 32 MB (dead after QKV)
  bf16* Q     = (bf16*)(ws + 56 * MB);   // 32 MB [b,h,l,d]
  bf16* KT    = (bf16*)(ws + 88 * MB);   // 32 MB [b,h,d,l]
  bf16* VT    = (bf16*)(ws + 120 * MB);  // 32 MB [b,h,d,l]
  float* pbuf = (float*)(ws + 24 * MB);  // 16 MB [8][32][128][128] (aliases dead xb)
  bf16* attn  = xb;                      // alias (written after kv/reduce done)
  bf16* hbuf  = (bf16*)(ws + 24 * MB);   // 128 MB [16384][4096]
  bf16* kvT   = (bf16*)(ws + 152 * MB);  // 1 MB
  float* ksum = (float*)(ws + 153 * MB); // 16 KB
  bf16* z     = (bf16*)(ws + 154 * MB);  // 32 MB
  bf16* z2    = z;
  bf16* y1    = (bf16*)(ws + 186 * MB);  // 32 MB

  k_conv_bf16<<<16384, 256, 0, stream>>>(x, xb);
  dim3 tb(32, 8);
  k_transpose_w<<<dim3(3072 / 32, 1024 / 32), tb, 0, stream>>>(Wqkv, WqkvT, 1024, 3072);
  k_transpose_w<<<dim3(1024 / 32, 1024 / 32), tb, 0, stream>>>(Wout, WoutT, 1024, 1024);
  k_transpose_w<<<dim3(4096 / 32, 1024 / 32), tb, 0, stream>>>(Wff1, Wff1T, 1024, 4096);
  k_transpose_w<<<dim3(1024 / 32, 4096 / 32), tb, 0, stream>>>(Wff2, Wff2T, 4096, 1024);

  // QKV projection (256^2 8-phase) + elu+1 fused scatter
  k256_qkv<<<(MTOK / 256) * (3072 / 256), 512, 0, stream>>>(xb, WqkvT, Q, KT, VT,
                                                            3072 / 256);
  // linear attention
  k_kv_split<<<256, 256, 0, stream>>>(KT, VT, pbuf);
  k_kv_reduce<<<2048, 256, 0, stream>>>(pbuf, kvT);
  k_ksum<<<4096, 256, 0, stream>>>(KT, ksum);
  k_attn_out<<<dim3(32, LL / BM), 256, 0, stream>>>(Q, kvT, ksum, attn);
  // W_out + residual(x)
  k256_wout<<<(MTOK / 256) * (1024 / 256), 512, 0, stream>>>(attn, WoutT, x, z,
                                                             1024 / 256);
  k_rmsnorm<bf16><<<MTOK, 256, 0, stream>>>(z, g1, y1);
  // FFN
  k256_ff1<<<(MTOK / 256) * (4096 / 256), 512, 0, stream>>>(y1, Wff1T, hbuf,
                                                            4096 / 256);
  k256_ff2<<<(MTOK / 256) * (1024 / 256), 512, 0, stream>>>(hbuf, Wff2T, y1, z2,
                                                            1024 / 256);
  k_rmsnorm<float><<<MTOK, 256, 0, stream>>>(z2, g2, out);
}